// Round 1
// baseline (302.464 us; speedup 1.0000x reference)
//
#include <hip/hip_runtime.h>
#include <stdint.h>

// GCN 2-hop: GEMMs via bf16 MFMA, aggregation via on-device CSR (no atomics in
// the hot loop), fused bias/relu/residual/LayerNorm epilogues.

constexpr int DIN = 128;
constexpr int DH  = 256;
#define LN_EPS 1e-5f

typedef __attribute__((ext_vector_type(8))) short bf16x8;  // 8 bf16 = 4 VGPR
typedef __attribute__((ext_vector_type(4))) short bf16x4;  // 8 bytes
typedef __attribute__((ext_vector_type(4))) float f32x4;

__device__ __forceinline__ short f2bf(float f) {
  union { float f; unsigned u; } v; v.f = f;
  unsigned r = v.u + 0x7fffu + ((v.u >> 16) & 1u);  // RNE
  return (short)(r >> 16);
}
__device__ __forceinline__ float bf2f(short b) {
  union { unsigned u; float f; } v; v.u = ((unsigned)(unsigned short)b) << 16;
  return v.f;
}

// ---------------- prep kernels ----------------

__global__ void k_init(float* deg, int* flag, int n) {
  int i = blockIdx.x * blockDim.x + threadIdx.x;
  if (i < n) deg[i] = 1.0f;              // self-loop weight
  if (i == 0) *flag = 1;                 // assume int64 until disproven
}

// edge_index may be int32 (JAX x64 disabled) or int64. If int32, the odd
// 32-bit words are edge values (src row) and will be nonzero somewhere.
__global__ void k_detect(const unsigned* ei, int nsample, int* flag) {
  int i = blockIdx.x * blockDim.x + threadIdx.x;
  if (i < nsample && ei[2 * i + 1] != 0u) *flag = 0;  // benign race, same value
}

__device__ __forceinline__ int eidx(const void* ei, long long e, int m64) {
  return m64 ? (int)((const long long*)ei)[e] : ((const int*)ei)[e];
}

__global__ void k_edge_accum(const void* ei, const float* w, float* deg,
                             int* cnt, const int* flag, int E) {
  int e = blockIdx.x * blockDim.x + threadIdx.x;
  if (e >= E) return;
  int m64 = *flag;
  int d = eidx(ei, (long long)E + e, m64);
  atomicAdd(&deg[d], w[e]);
  atomicAdd(&cnt[d], 1);
}

__global__ void k_dinv(float* deg, int n) {
  int i = blockIdx.x * blockDim.x + threadIdx.x;
  if (i < n) deg[i] = rsqrtf(deg[i]);    // deg >= 1 always (self loop)
}

// single-block exclusive scan of cnt[0..n) -> rowptr[0..n]
__global__ void k_scan(const int* cnt, int* rowptr, int n) {
  __shared__ int buf[1024];
  __shared__ int carry_s;
  int tid = threadIdx.x;
  if (tid == 0) { carry_s = 0; rowptr[0] = 0; }
  __syncthreads();
  int nchunk = (n + 1023) / 1024;
  for (int c = 0; c < nchunk; ++c) {
    int i = c * 1024 + tid;
    int v = (i < n) ? cnt[i] : 0;
    buf[tid] = v;
    __syncthreads();
    for (int off = 1; off < 1024; off <<= 1) {
      int t = (tid >= off) ? buf[tid - off] : 0;
      __syncthreads();
      buf[tid] += t;
      __syncthreads();
    }
    int total = buf[1023];
    int inc = buf[tid] + carry_s;        // inclusive scan + carry
    if (i < n) rowptr[i + 1] = inc;
    __syncthreads();
    if (tid == 0) carry_s += total;
    __syncthreads();
  }
}

__global__ void k_cursor(const int* rowptr, int* cursor, int n) {
  int i = blockIdx.x * blockDim.x + threadIdx.x;
  if (i < n) cursor[i] = rowptr[i];
}

__global__ void k_fill(const void* ei, const float* w, const float* dinv,
                       int* cursor, int* srcs, float* norms, const int* flag,
                       int E) {
  int e = blockIdx.x * blockDim.x + threadIdx.x;
  if (e >= E) return;
  int m64 = *flag;
  int s = eidx(ei, e, m64);
  int d = eidx(ei, (long long)E + e, m64);
  int p = atomicAdd(&cursor[d], 1);
  srcs[p] = s;
  norms[p] = dinv[s] * w[e] * dinv[d];
}

__global__ void k_cvt(const float* in, short* out, int n) {
  int i = blockIdx.x * blockDim.x + threadIdx.x;
  if (i < n) out[i] = f2bf(in[i]);
}

// W[K][DH] f32 (row-major) -> Wt[DH][K] bf16
__global__ void k_transpose_cvt(const float* W, short* Wt, int K) {
  int idx = blockIdx.x * blockDim.x + threadIdx.x;
  if (idx < K * DH) {
    int k = idx / DH, n = idx % DH;
    Wt[n * K + k] = f2bf(W[idx]);
  }
}

// ---------------- GEMM: C[M][256] = A[M][K] @ Bt[256][K]^T ----------------
// block = 64x64 tile, 4 waves each computing 32x32 via 2x2 mfma_16x16x32_bf16
// fragments. No LDS: A/B fragments read directly from global (cache-resident).

template <int K, bool BF16OUT, bool BIAS>
__global__ __launch_bounds__(256) void k_gemm(const short* __restrict__ A,
                                              const short* __restrict__ Bt,
                                              const float* __restrict__ bias,
                                              short* __restrict__ outb,
                                              float* __restrict__ outf, int M) {
  int tid = threadIdx.x;
  int wave = tid >> 6, lane = tid & 63;
  int lr = lane & 15, lg = lane >> 4;
  int bm = blockIdx.x * 64 + (wave >> 1) * 32;   // wave row base
  int bn = blockIdx.y * 64 + (wave & 1) * 32;    // wave col base

  int r0 = min(bm + lr, M - 1);
  int r1 = min(bm + 16 + lr, M - 1);
  const short* a0p = A + (long long)r0 * K + lg * 8;
  const short* a1p = A + (long long)r1 * K + lg * 8;
  const short* b0p = Bt + (long long)(bn + lr) * K + lg * 8;
  const short* b1p = Bt + (long long)(bn + 16 + lr) * K + lg * 8;

  f32x4 acc[2][2] = {};
#pragma unroll
  for (int ks = 0; ks < K / 32; ++ks) {
    bf16x8 a0 = *(const bf16x8*)(a0p + ks * 32);
    bf16x8 a1 = *(const bf16x8*)(a1p + ks * 32);
    bf16x8 b0 = *(const bf16x8*)(b0p + ks * 32);
    bf16x8 b1 = *(const bf16x8*)(b1p + ks * 32);
    acc[0][0] = __builtin_amdgcn_mfma_f32_16x16x32_bf16(a0, b0, acc[0][0], 0, 0, 0);
    acc[0][1] = __builtin_amdgcn_mfma_f32_16x16x32_bf16(a0, b1, acc[0][1], 0, 0, 0);
    acc[1][0] = __builtin_amdgcn_mfma_f32_16x16x32_bf16(a1, b0, acc[1][0], 0, 0, 0);
    acc[1][1] = __builtin_amdgcn_mfma_f32_16x16x32_bf16(a1, b1, acc[1][1], 0, 0, 0);
  }

#pragma unroll
  for (int mi = 0; mi < 2; ++mi)
#pragma unroll
    for (int ni = 0; ni < 2; ++ni)
#pragma unroll
      for (int j = 0; j < 4; ++j) {
        int row = bm + mi * 16 + lg * 4 + j;   // D: row = (lane>>4)*4 + reg
        int col = bn + ni * 16 + lr;           // D: col = lane&15
        if (row < M) {
          float v = acc[mi][ni][j];
          if (BIAS) v += bias[col];
          if (BF16OUT) outb[(long long)row * DH + col] = f2bf(v);
          else         outf[(long long)row * DH + col] = v;
        }
      }
}

// ------------- fused aggregation + bias (+relu) + residual + LayerNorm ------
// one wave per destination node; each lane owns 4 of the 256 dims.

template <bool RELU>
__global__ __launch_bounds__(64) void k_agg_ln(
    const short* __restrict__ H, const float* __restrict__ resid,
    const float* __restrict__ bias, const float* __restrict__ gamma,
    const float* __restrict__ beta, const int* __restrict__ rowptr,
    const int* __restrict__ srcs, const float* __restrict__ norms,
    const float* __restrict__ dinv, float* __restrict__ out_f,
    short* __restrict__ out_bf, int n) {
  int i = blockIdx.x;
  int lane = threadIdx.x;
  int d = lane * 4;

  float di = dinv[i];
  float acc0, acc1, acc2, acc3;
  {
    bf16x4 hv = *(const bf16x4*)(H + (long long)i * DH + d);
    float sw = di * di;  // self-loop norm
    acc0 = sw * bf2f(hv[0]); acc1 = sw * bf2f(hv[1]);
    acc2 = sw * bf2f(hv[2]); acc3 = sw * bf2f(hv[3]);
  }
  int e = rowptr[i], end = rowptr[i + 1];
  for (; e < end; ++e) {
    int s = srcs[e];
    float nm = norms[e];
    bf16x4 v = *(const bf16x4*)(H + (long long)s * DH + d);
    acc0 += nm * bf2f(v[0]); acc1 += nm * bf2f(v[1]);
    acc2 += nm * bf2f(v[2]); acc3 += nm * bf2f(v[3]);
  }

  f32x4 rv = *(const f32x4*)(resid + (long long)i * DH + d);
  f32x4 bv = *(const f32x4*)(bias + d);
  float t0 = acc0 + bv[0], t1 = acc1 + bv[1], t2 = acc2 + bv[2], t3 = acc3 + bv[3];
  if (RELU) {
    t0 = fmaxf(t0, 0.f); t1 = fmaxf(t1, 0.f);
    t2 = fmaxf(t2, 0.f); t3 = fmaxf(t3, 0.f);
  }
  t0 += rv[0]; t1 += rv[1]; t2 += rv[2]; t3 += rv[3];

  float s1 = t0 + t1 + t2 + t3;
  float s2 = t0 * t0 + t1 * t1 + t2 * t2 + t3 * t3;
  for (int m = 1; m < 64; m <<= 1) {
    s1 += __shfl_xor(s1, m, 64);
    s2 += __shfl_xor(s2, m, 64);
  }
  float mu = s1 * (1.f / 256.f);
  float var = s2 * (1.f / 256.f) - mu * mu;
  float rs = rsqrtf(var + LN_EPS);

  f32x4 gv = *(const f32x4*)(gamma + d);
  f32x4 be = *(const f32x4*)(beta + d);
  f32x4 y;
  y[0] = (t0 - mu) * rs * gv[0] + be[0];
  y[1] = (t1 - mu) * rs * gv[1] + be[1];
  y[2] = (t2 - mu) * rs * gv[2] + be[2];
  y[3] = (t3 - mu) * rs * gv[3] + be[3];
  *(f32x4*)(out_f + (long long)i * DH + d) = y;
  if (out_bf) {
    bf16x4 ob;
    ob[0] = f2bf(y[0]); ob[1] = f2bf(y[1]);
    ob[2] = f2bf(y[2]); ob[3] = f2bf(y[3]);
    *(bf16x4*)(out_bf + (long long)i * DH + d) = ob;
  }
}

// ---------------- launcher ----------------

extern "C" void kernel_launch(void* const* d_in, const int* in_sizes, int n_in,
                              void* d_out, int out_size, void* d_ws,
                              size_t ws_size, hipStream_t stream) {
  const float* x    = (const float*)d_in[0];
  const void*  ei   = d_in[1];
  const float* ew   = (const float*)d_in[2];
  const float* W1   = (const float*)d_in[3];
  const float* b1   = (const float*)d_in[4];
  const float* W2   = (const float*)d_in[5];
  const float* b2   = (const float*)d_in[6];
  const float* Wres = (const float*)d_in[7];
  const float* bres = (const float*)d_in[8];
  const float* g1   = (const float*)d_in[9];
  const float* be1  = (const float*)d_in[10];
  const float* g2   = (const float*)d_in[11];
  const float* be2  = (const float*)d_in[12];

  const int N = in_sizes[0] / DIN;
  const int E = in_sizes[2];

  char* ws = (char*)d_ws;
  auto alloc = [&](size_t bytes) -> char* {
    char* p = ws;
    ws += (bytes + 255) & ~(size_t)255;
    return p;
  };
  short* xb     = (short*)alloc((size_t)N * DIN * 2);
  short* W1t    = (short*)alloc((size_t)DIN * DH * 2);
  short* Wrt    = (short*)alloc((size_t)DIN * DH * 2);
  short* W2t    = (short*)alloc((size_t)DH * DH * 2);
  short* Hb     = (short*)alloc((size_t)N * DH * 2);  // H1bf, reused as H2bf
  float* RES    = (float*)alloc((size_t)N * DH * 4);
  float* h1f    = (float*)alloc((size_t)N * DH * 4);
  short* h1b    = (short*)alloc((size_t)N * DH * 2);
  float* deg    = (float*)alloc((size_t)N * 4);       // becomes dinv in place
  int*   cnt    = (int*)alloc((size_t)N * 4);
  int*   rowptr = (int*)alloc((size_t)(N + 1) * 4);
  int*   cursor = (int*)alloc((size_t)N * 4);
  int*   srcs   = (int*)alloc((size_t)E * 4);
  float* norms  = (float*)alloc((size_t)E * 4);
  int*   flag   = (int*)alloc(256);

  const int nb = (N + 255) / 256;
  const int eb = (E + 255) / 256;

  hipMemsetAsync(cnt, 0, (size_t)N * 4, stream);
  k_init<<<nb, 256, 0, stream>>>(deg, flag, N);
  k_detect<<<16, 256, 0, stream>>>((const unsigned*)ei, 4096, flag);
  k_edge_accum<<<eb, 256, 0, stream>>>(ei, ew, deg, cnt, flag, E);
  k_dinv<<<nb, 256, 0, stream>>>(deg, N);
  k_scan<<<1, 1024, 0, stream>>>(cnt, rowptr, N);
  k_cursor<<<nb, 256, 0, stream>>>(rowptr, cursor, N);
  k_fill<<<eb, 256, 0, stream>>>(ei, ew, deg, cursor, srcs, norms, flag, E);

  k_cvt<<<(N * DIN + 255) / 256, 256, 0, stream>>>(x, xb, N * DIN);
  k_transpose_cvt<<<(DIN * DH + 255) / 256, 256, 0, stream>>>(W1, W1t, DIN);
  k_transpose_cvt<<<(DIN * DH + 255) / 256, 256, 0, stream>>>(Wres, Wrt, DIN);
  k_transpose_cvt<<<(DH * DH + 255) / 256, 256, 0, stream>>>(W2, W2t, DH);

  dim3 gg((N + 63) / 64, DH / 64);
  // layer 1: H1 = x@W1 (bf16 out), RES = x@Wres + bres (f32 out)
  k_gemm<DIN, true, false><<<gg, 256, 0, stream>>>(xb, W1t, nullptr, Hb, nullptr, N);
  k_gemm<DIN, false, true><<<gg, 256, 0, stream>>>(xb, Wrt, bres, nullptr, RES, N);
  k_agg_ln<true><<<N, 64, 0, stream>>>(Hb, RES, b1, g1, be1, rowptr, srcs,
                                       norms, deg, h1f, h1b, N);
  // layer 2: H2 = h1@W2 (bf16 out), then agg + residual + LN -> d_out
  k_gemm<DH, true, false><<<gg, 256, 0, stream>>>(h1b, W2t, nullptr, Hb, nullptr, N);
  k_agg_ln<false><<<N, 64, 0, stream>>>(Hb, h1f, b2, g2, be2, rowptr, srcs,
                                        norms, deg, (float*)d_out, nullptr, N);
}

// Round 2
// 264.651 us; speedup vs baseline: 1.1429x; 1.1429x over previous
//
#include <hip/hip_runtime.h>
#include <stdint.h>

// GCN 2-hop: GEMMs via bf16 MFMA, aggregation via on-device CSR (no atomics in
// the hot loop), fused bias/relu/residual/LayerNorm epilogues.
// R2: 8 dispatches (was 15): fused prep/cvt, shfl-scan, fused layer-1 GEMM,
// 4-way-unrolled gather with 4 waves/WG.

constexpr int DIN = 128;
constexpr int DH  = 256;
#define LN_EPS 1e-5f

typedef __attribute__((ext_vector_type(8))) short bf16x8;  // 8 bf16 = 4 VGPR
typedef __attribute__((ext_vector_type(4))) short bf16x4;  // 8 bytes
typedef __attribute__((ext_vector_type(4))) float f32x4;

__device__ __forceinline__ short f2bf(float f) {
  union { float f; unsigned u; } v; v.f = f;
  unsigned r = v.u + 0x7fffu + ((v.u >> 16) & 1u);  // RNE
  return (short)(r >> 16);
}
__device__ __forceinline__ float bf2f(short b) {
  union { unsigned u; float f; } v; v.u = ((unsigned)(unsigned short)b) << 16;
  return v.f;
}

// edge_index may be int32 (JAX x64 off) or int64. Wave-level probe: sample 64
// odd 32-bit words of the src half; all-zero <=> int64 high words. Must be
// called with ALL 64 lanes active (before any bounds-check return).
__device__ __forceinline__ int probe_m64(const unsigned* ei) {
  int lane = threadIdx.x & 63;
  unsigned v = ei[2 * (lane * 32) + 1];
  return __ballot(v != 0u) == 0ull;
}

__device__ __forceinline__ int eidx(const void* ei, long long e, int m64) {
  return m64 ? (int)((const long long*)ei)[e] : ((const int*)ei)[e];
}

// ---------------- prep: deg/cnt init + x->bf16 + 3 weight transposes --------

__global__ __launch_bounds__(256) void k_prep(const float* __restrict__ x,
                                              short* __restrict__ xb,
                                              const float* __restrict__ W1,
                                              const float* __restrict__ Wres,
                                              const float* __restrict__ W2,
                                              short* __restrict__ W1t,
                                              short* __restrict__ Wrt,
                                              short* __restrict__ W2t,
                                              float* __restrict__ deg,
                                              int* __restrict__ cnt, int N) {
  const int NXV = N * DIN / 8;           // x in 8-float chunks
  const int NW  = DIN * DH;              // 32768
  const int NW2 = DH * DH;               // 65536
  int idx = blockIdx.x * 256 + threadIdx.x;
  if (idx < NXV) {
    f32x4 a = ((const f32x4*)x)[idx * 2];
    f32x4 b = ((const f32x4*)x)[idx * 2 + 1];
    bf16x8 o;
    o[0] = f2bf(a[0]); o[1] = f2bf(a[1]); o[2] = f2bf(a[2]); o[3] = f2bf(a[3]);
    o[4] = f2bf(b[0]); o[5] = f2bf(b[1]); o[6] = f2bf(b[2]); o[7] = f2bf(b[3]);
    ((bf16x8*)xb)[idx] = o;
    return;
  }
  idx -= NXV;
  if (idx < N) { deg[idx] = 1.0f; cnt[idx] = 0; return; }
  idx -= N;
  if (idx < NW) {  // W1t[n][k] = W1[k][n], write-coalesced
    int n = idx / DIN, k = idx % DIN;
    W1t[idx] = f2bf(W1[k * DH + n]);
    return;
  }
  idx -= NW;
  if (idx < NW) {
    int n = idx / DIN, k = idx % DIN;
    Wrt[idx] = f2bf(Wres[k * DH + n]);
    return;
  }
  idx -= NW;
  if (idx < NW2) {
    int n = idx / DH, k = idx % DH;
    W2t[idx] = f2bf(W2[k * DH + n]);
  }
}

// ---------------- edge accumulation (deg, cnt) ----------------

__global__ __launch_bounds__(256) void k_edge_accum(const void* ei,
                                                    const float* __restrict__ w,
                                                    float* deg, int* cnt, int E) {
  int m64 = probe_m64((const unsigned*)ei);   // all lanes active here
  int e = blockIdx.x * 256 + threadIdx.x;
  if (e >= E) return;
  int d = eidx(ei, (long long)E + e, m64);
  atomicAdd(&deg[d], w[e]);
  atomicAdd(&cnt[d], 1);
}

// ------------- single block: dinv (in place) + scan cnt -> rowptr, cursor ---

__global__ __launch_bounds__(1024) void k_scan(const int* __restrict__ cnt,
                                               float* deg, int* rowptr,
                                               int* cursor, int n) {
  for (int i = threadIdx.x; i < n; i += 1024) deg[i] = rsqrtf(deg[i]);

  __shared__ int wsum[16];
  __shared__ int carry_s;
  int tid = threadIdx.x, lane = tid & 63, wv = tid >> 6;
  if (tid == 0) { carry_s = 0; rowptr[0] = 0; cursor[0] = 0; }
  __syncthreads();
  for (int c0 = 0; c0 < n; c0 += 1024) {
    int i = c0 + tid;
    int sc = (i < n) ? cnt[i] : 0;
#pragma unroll
    for (int off = 1; off < 64; off <<= 1) {
      int t = __shfl_up(sc, off, 64);
      if (lane >= off) sc += t;
    }
    if (lane == 63) wsum[wv] = sc;
    __syncthreads();
    if (wv == 0) {
      int s = (lane < 16) ? wsum[lane] : 0;
#pragma unroll
      for (int off = 1; off < 16; off <<= 1) {
        int t = __shfl_up(s, off, 64);
        if (lane >= off) s += t;
      }
      if (lane < 16) wsum[lane] = s;
    }
    __syncthreads();
    int inc = sc + ((wv > 0) ? wsum[wv - 1] : 0) + carry_s;
    if (i < n) { rowptr[i + 1] = inc; cursor[i + 1] = inc; }
    __syncthreads();
    if (tid == 0) carry_s += wsum[15];
    __syncthreads();
  }
}

// ---------------- CSR fill ----------------

__global__ __launch_bounds__(256) void k_fill(const void* ei,
                                              const float* __restrict__ w,
                                              const float* __restrict__ dinv,
                                              int* cursor, int* srcs,
                                              float* norms, int E) {
  int m64 = probe_m64((const unsigned*)ei);
  int e = blockIdx.x * 256 + threadIdx.x;
  if (e >= E) return;
  int s = eidx(ei, e, m64);
  int d = eidx(ei, (long long)E + e, m64);
  int p = atomicAdd(&cursor[d], 1);
  srcs[p] = s;
  norms[p] = dinv[s] * w[e] * dinv[d];
}

// ------------- layer-1 fused GEMM: H1 = A@W1 (bf16), RES = A@Wres+bres (f32) -
// 64x64 block tile, 4 waves of 32x32 via 2x2 mfma_16x16x32_bf16. No LDS.

__global__ __launch_bounds__(256) void k_gemm_l1(const short* __restrict__ A,
                                                 const short* __restrict__ B1,
                                                 const short* __restrict__ Br,
                                                 const float* __restrict__ bres,
                                                 short* __restrict__ H1,
                                                 float* __restrict__ RES, int M) {
  constexpr int K = DIN;
  int tid = threadIdx.x;
  int wave = tid >> 6, lane = tid & 63;
  int lr = lane & 15, lg = lane >> 4;
  int bm = blockIdx.x * 64 + (wave >> 1) * 32;
  int bn = blockIdx.y * 64 + (wave & 1) * 32;

  int r0 = min(bm + lr, M - 1);
  int r1 = min(bm + 16 + lr, M - 1);
  const short* a0p = A + (long long)r0 * K + lg * 8;
  const short* a1p = A + (long long)r1 * K + lg * 8;
  const short* b10p = B1 + (long long)(bn + lr) * K + lg * 8;
  const short* b11p = B1 + (long long)(bn + 16 + lr) * K + lg * 8;
  const short* br0p = Br + (long long)(bn + lr) * K + lg * 8;
  const short* br1p = Br + (long long)(bn + 16 + lr) * K + lg * 8;

  f32x4 a1c[2][2] = {}, arc[2][2] = {};
#pragma unroll
  for (int ks = 0; ks < K / 32; ++ks) {
    bf16x8 a0 = *(const bf16x8*)(a0p + ks * 32);
    bf16x8 a1 = *(const bf16x8*)(a1p + ks * 32);
    bf16x8 p0 = *(const bf16x8*)(b10p + ks * 32);
    bf16x8 p1 = *(const bf16x8*)(b11p + ks * 32);
    bf16x8 q0 = *(const bf16x8*)(br0p + ks * 32);
    bf16x8 q1 = *(const bf16x8*)(br1p + ks * 32);
    a1c[0][0] = __builtin_amdgcn_mfma_f32_16x16x32_bf16(a0, p0, a1c[0][0], 0, 0, 0);
    a1c[0][1] = __builtin_amdgcn_mfma_f32_16x16x32_bf16(a0, p1, a1c[0][1], 0, 0, 0);
    a1c[1][0] = __builtin_amdgcn_mfma_f32_16x16x32_bf16(a1, p0, a1c[1][0], 0, 0, 0);
    a1c[1][1] = __builtin_amdgcn_mfma_f32_16x16x32_bf16(a1, p1, a1c[1][1], 0, 0, 0);
    arc[0][0] = __builtin_amdgcn_mfma_f32_16x16x32_bf16(a0, q0, arc[0][0], 0, 0, 0);
    arc[0][1] = __builtin_amdgcn_mfma_f32_16x16x32_bf16(a0, q1, arc[0][1], 0, 0, 0);
    arc[1][0] = __builtin_amdgcn_mfma_f32_16x16x32_bf16(a1, q0, arc[1][0], 0, 0, 0);
    arc[1][1] = __builtin_amdgcn_mfma_f32_16x16x32_bf16(a1, q1, arc[1][1], 0, 0, 0);
  }

#pragma unroll
  for (int mi = 0; mi < 2; ++mi)
#pragma unroll
    for (int ni = 0; ni < 2; ++ni)
#pragma unroll
      for (int j = 0; j < 4; ++j) {
        int row = bm + mi * 16 + lg * 4 + j;
        int col = bn + ni * 16 + lr;
        if (row < M) {
          H1[(long long)row * DH + col] = f2bf(a1c[mi][ni][j]);
          RES[(long long)row * DH + col] = arc[mi][ni][j] + bres[col];
        }
      }
}

// ---------------- layer-2 GEMM: H2 = A@W2t^T (bf16 out) ----------------

__global__ __launch_bounds__(256) void k_gemm2(const short* __restrict__ A,
                                               const short* __restrict__ Bt,
                                               short* __restrict__ outb, int M) {
  constexpr int K = DH;
  int tid = threadIdx.x;
  int wave = tid >> 6, lane = tid & 63;
  int lr = lane & 15, lg = lane >> 4;
  int bm = blockIdx.x * 64 + (wave >> 1) * 32;
  int bn = blockIdx.y * 64 + (wave & 1) * 32;

  int r0 = min(bm + lr, M - 1);
  int r1 = min(bm + 16 + lr, M - 1);
  const short* a0p = A + (long long)r0 * K + lg * 8;
  const short* a1p = A + (long long)r1 * K + lg * 8;
  const short* b0p = Bt + (long long)(bn + lr) * K + lg * 8;
  const short* b1p = Bt + (long long)(bn + 16 + lr) * K + lg * 8;

  f32x4 acc[2][2] = {};
#pragma unroll
  for (int ks = 0; ks < K / 32; ++ks) {
    bf16x8 a0 = *(const bf16x8*)(a0p + ks * 32);
    bf16x8 a1 = *(const bf16x8*)(a1p + ks * 32);
    bf16x8 b0 = *(const bf16x8*)(b0p + ks * 32);
    bf16x8 b1 = *(const bf16x8*)(b1p + ks * 32);
    acc[0][0] = __builtin_amdgcn_mfma_f32_16x16x32_bf16(a0, b0, acc[0][0], 0, 0, 0);
    acc[0][1] = __builtin_amdgcn_mfma_f32_16x16x32_bf16(a0, b1, acc[0][1], 0, 0, 0);
    acc[1][0] = __builtin_amdgcn_mfma_f32_16x16x32_bf16(a1, b0, acc[1][0], 0, 0, 0);
    acc[1][1] = __builtin_amdgcn_mfma_f32_16x16x32_bf16(a1, b1, acc[1][1], 0, 0, 0);
  }

#pragma unroll
  for (int mi = 0; mi < 2; ++mi)
#pragma unroll
    for (int ni = 0; ni < 2; ++ni)
#pragma unroll
      for (int j = 0; j < 4; ++j) {
        int row = bm + mi * 16 + lg * 4 + j;
        int col = bn + ni * 16 + lr;
        if (row < M) outb[(long long)row * DH + col] = f2bf(acc[mi][ni][j]);
      }
}

// ------------- fused aggregation + bias (+relu) + residual + LayerNorm ------
// 4 waves/WG, one wave per destination node; lane owns 4 of 256 dims.
// Gather unrolled x4 for memory-level parallelism.

template <bool RELU>
__global__ __launch_bounds__(256) void k_agg_ln(
    const short* __restrict__ H, const float* __restrict__ resid,
    const float* __restrict__ bias, const float* __restrict__ gamma,
    const float* __restrict__ beta, const int* __restrict__ rowptr,
    const int* __restrict__ srcs, const float* __restrict__ norms,
    const float* __restrict__ dinv, float* __restrict__ out_f,
    short* __restrict__ out_bf, int n) {
  int wv = threadIdx.x >> 6, lane = threadIdx.x & 63;
  int i = blockIdx.x * 4 + wv;
  if (i >= n) return;
  int d = lane * 4;

  float di = dinv[i];
  float acc0, acc1, acc2, acc3;
  {
    bf16x4 hv = *(const bf16x4*)(H + (long long)i * DH + d);
    float sw = di * di;  // self-loop norm
    acc0 = sw * bf2f(hv[0]); acc1 = sw * bf2f(hv[1]);
    acc2 = sw * bf2f(hv[2]); acc3 = sw * bf2f(hv[3]);
  }
  int e = rowptr[i], end = rowptr[i + 1];
  for (; e + 4 <= end; e += 4) {
    int s0 = srcs[e], s1 = srcs[e + 1], s2 = srcs[e + 2], s3 = srcs[e + 3];
    float n0 = norms[e], n1 = norms[e + 1], n2 = norms[e + 2], n3 = norms[e + 3];
    bf16x4 v0 = *(const bf16x4*)(H + (long long)s0 * DH + d);
    bf16x4 v1 = *(const bf16x4*)(H + (long long)s1 * DH + d);
    bf16x4 v2 = *(const bf16x4*)(H + (long long)s2 * DH + d);
    bf16x4 v3 = *(const bf16x4*)(H + (long long)s3 * DH + d);
    acc0 += n0 * bf2f(v0[0]); acc1 += n0 * bf2f(v0[1]);
    acc2 += n0 * bf2f(v0[2]); acc3 += n0 * bf2f(v0[3]);
    acc0 += n1 * bf2f(v1[0]); acc1 += n1 * bf2f(v1[1]);
    acc2 += n1 * bf2f(v1[2]); acc3 += n1 * bf2f(v1[3]);
    acc0 += n2 * bf2f(v2[0]); acc1 += n2 * bf2f(v2[1]);
    acc2 += n2 * bf2f(v2[2]); acc3 += n2 * bf2f(v2[3]);
    acc0 += n3 * bf2f(v3[0]); acc1 += n3 * bf2f(v3[1]);
    acc2 += n3 * bf2f(v3[2]); acc3 += n3 * bf2f(v3[3]);
  }
  for (; e < end; ++e) {
    int s = srcs[e];
    float nm = norms[e];
    bf16x4 v = *(const bf16x4*)(H + (long long)s * DH + d);
    acc0 += nm * bf2f(v[0]); acc1 += nm * bf2f(v[1]);
    acc2 += nm * bf2f(v[2]); acc3 += nm * bf2f(v[3]);
  }

  f32x4 rv = *(const f32x4*)(resid + (long long)i * DH + d);
  f32x4 bv = *(const f32x4*)(bias + d);
  float t0 = acc0 + bv[0], t1 = acc1 + bv[1], t2 = acc2 + bv[2], t3 = acc3 + bv[3];
  if (RELU) {
    t0 = fmaxf(t0, 0.f); t1 = fmaxf(t1, 0.f);
    t2 = fmaxf(t2, 0.f); t3 = fmaxf(t3, 0.f);
  }
  t0 += rv[0]; t1 += rv[1]; t2 += rv[2]; t3 += rv[3];

  float s1 = t0 + t1 + t2 + t3;
  float s2 = t0 * t0 + t1 * t1 + t2 * t2 + t3 * t3;
#pragma unroll
  for (int m = 1; m < 64; m <<= 1) {
    s1 += __shfl_xor(s1, m, 64);
    s2 += __shfl_xor(s2, m, 64);
  }
  float mu = s1 * (1.f / 256.f);
  float var = s2 * (1.f / 256.f) - mu * mu;
  float rs = rsqrtf(var + LN_EPS);

  f32x4 gv = *(const f32x4*)(gamma + d);
  f32x4 be = *(const f32x4*)(beta + d);
  f32x4 y;
  y[0] = (t0 - mu) * rs * gv[0] + be[0];
  y[1] = (t1 - mu) * rs * gv[1] + be[1];
  y[2] = (t2 - mu) * rs * gv[2] + be[2];
  y[3] = (t3 - mu) * rs * gv[3] + be[3];
  *(f32x4*)(out_f + (long long)i * DH + d) = y;
  if (out_bf) {
    bf16x4 ob;
    ob[0] = f2bf(y[0]); ob[1] = f2bf(y[1]);
    ob[2] = f2bf(y[2]); ob[3] = f2bf(y[3]);
    *(bf16x4*)(out_bf + (long long)i * DH + d) = ob;
  }
}

// ---------------- launcher ----------------

extern "C" void kernel_launch(void* const* d_in, const int* in_sizes, int n_in,
                              void* d_out, int out_size, void* d_ws,
                              size_t ws_size, hipStream_t stream) {
  const float* x    = (const float*)d_in[0];
  const void*  ei   = d_in[1];
  const float* ew   = (const float*)d_in[2];
  const float* W1   = (const float*)d_in[3];
  const float* b1   = (const float*)d_in[4];
  const float* W2   = (const float*)d_in[5];
  const float* b2   = (const float*)d_in[6];
  const float* Wres = (const float*)d_in[7];
  const float* bres = (const float*)d_in[8];
  const float* g1   = (const float*)d_in[9];
  const float* be1  = (const float*)d_in[10];
  const float* g2   = (const float*)d_in[11];
  const float* be2  = (const float*)d_in[12];

  const int N = in_sizes[0] / DIN;
  const int E = in_sizes[2];

  char* ws = (char*)d_ws;
  auto alloc = [&](size_t bytes) -> char* {
    char* p = ws;
    ws += (bytes + 255) & ~(size_t)255;
    return p;
  };
  short* xb     = (short*)alloc((size_t)N * DIN * 2);
  short* W1t    = (short*)alloc((size_t)DIN * DH * 2);
  short* Wrt    = (short*)alloc((size_t)DIN * DH * 2);
  short* W2t    = (short*)alloc((size_t)DH * DH * 2);
  short* Hb     = (short*)alloc((size_t)N * DH * 2);  // H1bf, reused as H2bf
  float* RES    = (float*)alloc((size_t)N * DH * 4);
  float* h1f    = (float*)alloc((size_t)N * DH * 4);
  short* h1b    = (short*)alloc((size_t)N * DH * 2);
  float* deg    = (float*)alloc((size_t)N * 4);       // becomes dinv in place
  int*   cnt    = (int*)alloc((size_t)N * 4);
  int*   rowptr = (int*)alloc((size_t)(N + 1) * 4);
  int*   cursor = (int*)alloc((size_t)(N + 1) * 4);
  int*   srcs   = (int*)alloc((size_t)E * 4);
  float* norms  = (float*)alloc((size_t)E * 4);

  const int eb = (E + 255) / 256;

  // prep: x cvt + weight transposes + deg/cnt init, one kernel
  int prep_items = N * DIN / 8 + N + 2 * DIN * DH + DH * DH;
  k_prep<<<(prep_items + 255) / 256, 256, 0, stream>>>(
      x, xb, W1, Wres, W2, W1t, Wrt, W2t, deg, cnt, N);
  k_edge_accum<<<eb, 256, 0, stream>>>(ei, ew, deg, cnt, E);
  k_scan<<<1, 1024, 0, stream>>>(cnt, deg, rowptr, cursor, N);
  k_fill<<<eb, 256, 0, stream>>>(ei, ew, deg, cursor, srcs, norms, E);

  dim3 gg((N + 63) / 64, DH / 64);
  k_gemm_l1<<<gg, 256, 0, stream>>>(xb, W1t, Wrt, bres, Hb, RES, N);
  k_agg_ln<true><<<(N + 3) / 4, 256, 0, stream>>>(Hb, RES, b1, g1, be1, rowptr,
                                                  srcs, norms, deg, h1f, h1b, N);
  k_gemm2<<<gg, 256, 0, stream>>>(h1b, W2t, Hb, N);
  k_agg_ln<false><<<(N + 3) / 4, 256, 0, stream>>>(Hb, h1f, b2, g2, be2, rowptr,
                                                   srcs, norms, deg,
                                                   (float*)d_out, nullptr, N);
}